// Round 6
// baseline (186.608 us; speedup 1.0000x reference)
//
#include <hip/hip_runtime.h>
#include <hip/hip_bf16.h>
#include <math.h>

#define NP 1024
#define R 32
#define C 16
#define GAMMA (32.0f/3.5f)
#define DC (3.5f/31.0f)

typedef __attribute__((ext_vector_type(8))) short bf16x8;
typedef __attribute__((ext_vector_type(4))) float f32x4;
typedef __attribute__((ext_vector_type(4))) unsigned u32x4;

// Fast RNE float->bf16 for FINITE values (no NaN path): ~3 insts.
__device__ __forceinline__ unsigned bfbits(float x){
    unsigned u = __builtin_bit_cast(unsigned, x);
    return u + 0x7FFFu + ((u >> 16) & 1u);
}
__device__ __forceinline__ short tobf(float x){
    return (short)(bfbits(x) >> 16);
}
__device__ __forceinline__ float frombf(short s){
    const unsigned u = ((unsigned)(unsigned short)s) << 16;
    return __builtin_bit_cast(float, u);
}
// pack two floats as bf16 pair: a -> low short, b -> high short (~7 insts)
__device__ __forceinline__ unsigned pack2bf(float a, float b){
    return (bfbits(a) >> 16) | (bfbits(b) & 0xFFFF0000u);
}
__device__ __forceinline__ float eluf(float x){ return x > 0.f ? x : expm1f(x); }

__device__ __forceinline__ f32x4 mfma16(bf16x8 a, bf16x8 b, f32x4 c){
    return __builtin_amdgcn_mfma_f32_16x16x32_bf16(a, b, c, 0, 0, 0);
}

// Build the rbf A-fragment for row-distance dij, k = q*8 + jj (jj=0..7).
__device__ __forceinline__ bf16x8 make_afrag(float dij, int q){
    u32x4 av;
    #pragma unroll
    for (int p = 0; p < 4; p++){
        const float t0 = dij - (float)(q*8 + 2*p)*DC;
        const float t1 = dij - (float)(q*8 + 2*p + 1)*DC;
        av[p] = pack2bf(__expf(-GAMMA*t0*t0), __expf(-GAMMA*t1*t1));
    }
    return __builtin_bit_cast(bf16x8, av);
}

// B-operand fragment: element jj = src[(q*8+jj)*STRIDE + n]. bf16 hi+lo split
// keeps weight rounding at ~fp32 level (2 MFMAs per GEMM).
template<int STRIDE>
__device__ __forceinline__ void load_bfrag(const float* __restrict__ src, int q, int n,
                                           bf16x8& hi, bf16x8& lo){
    #pragma unroll
    for (int jj = 0; jj < 8; jj++){
        const float w = src[(q*8+jj)*STRIDE + n];
        const short h = tobf(w);
        hi[jj] = h;
        lo[jj] = tobf(w - frombf(h));
    }
}

// ---------------------------------------------------------------------------
// Layer 1 (MFMA, barrier-free K-loop, SPLIT-K x2): block = (a, half); each
// block covers 8 b-tiles (512 b's). Partial outputs per half; k_point1 sums.
// ---------------------------------------------------------------------------
__global__ __launch_bounds__(256) void k_layer1(
    const float* __restrict__ points,
    const float* __restrict__ W1, const float* __restrict__ B1,
    const float* __restrict__ W2, const float* __restrict__ B2,
    float* __restrict__ out0h, float* __restrict__ out1h)
{
    __shared__ float sS0[4][32];
    __shared__ float sT[4][32][3];
    __shared__ float sUp[4][3];

    const int tid  = threadIdx.x;
    const int lane = tid & 63;
    const int wv   = tid >> 6;
    const int l16  = lane & 15;
    const int q    = lane >> 4;
    const int a    = blockIdx.x >> 1;
    const int half = blockIdx.x & 1;
    const float pax = points[a*3+0], pay = points[a*3+1], paz = points[a*3+2];

    bf16x8 w1hi[2][2], w1lo[2][2];
    float  b1v[2][2];
    #pragma unroll
    for (int fi = 0; fi < 2; fi++)
        #pragma unroll
        for (int nt = 0; nt < 2; nt++){
            load_bfrag<R>(W1 + fi*R*R, q, nt*16 + l16, w1hi[fi][nt], w1lo[fi][nt]);
            b1v[fi][nt] = B1[fi*R + nt*16 + l16];
        }

    float s0a[2] = {0.f, 0.f};
    float T[2][3] = {};
    float upx = 0.f, upy = 0.f, upz = 0.f;

    for (int bt = half*8; bt < half*8 + 8; bt++){
        const int bA = bt*64 + wv*16 + l16;
        const float rx = pax - points[bA*3+0];
        const float ry = pay - points[bA*3+1];
        const float rz = paz - points[bA*3+2];
        const float ss = rx*rx + ry*ry + rz*rz;
        const float dij = sqrtf(ss);
        const float inv = 1.0f / sqrtf(fmaxf(ss, 1e-8f));
        const float ux = rx*inv, uy = ry*inv, uz = rz*inv;  // ==0 on diagonal
        upx += ux; upy += uy; upz += uz;                    // 4x overcount, /4 later

        const bf16x8 afrag = make_afrag(dij, q);

        float uxr[4], uyr[4], uzr[4];
        #pragma unroll
        for (int r4 = 0; r4 < 4; r4++){
            const int sl = q*4 + r4;
            uxr[r4] = __shfl(ux, sl, 16);
            uyr[r4] = __shfl(uy, sl, 16);
            uzr[r4] = __shfl(uz, sl, 16);
        }

        #pragma unroll
        for (int nt = 0; nt < 2; nt++){
            f32x4 c = {b1v[0][nt], b1v[0][nt], b1v[0][nt], b1v[0][nt]};
            c = mfma16(afrag, w1hi[0][nt], c);
            c = mfma16(afrag, w1lo[0][nt], c);
            s0a[nt] += fmaxf(c[0],0.f)+fmaxf(c[1],0.f)+fmaxf(c[2],0.f)+fmaxf(c[3],0.f);
        }
        #pragma unroll
        for (int nt = 0; nt < 2; nt++){
            f32x4 c = {b1v[1][nt], b1v[1][nt], b1v[1][nt], b1v[1][nt]};
            c = mfma16(afrag, w1hi[1][nt], c);
            c = mfma16(afrag, w1lo[1][nt], c);
            #pragma unroll
            for (int r4 = 0; r4 < 4; r4++){
                const float h = fmaxf(c[r4], 0.f);
                T[nt][0] = fmaf(h, uxr[r4], T[nt][0]);
                T[nt][1] = fmaf(h, uyr[r4], T[nt][1]);
                T[nt][2] = fmaf(h, uzr[r4], T[nt][2]);
            }
        }
    }

    // cross-quad reduce (rows live in quads)
    #pragma unroll
    for (int nt = 0; nt < 2; nt++){
        s0a[nt] += __shfl_down(s0a[nt], 32, 64);
        s0a[nt] += __shfl_down(s0a[nt], 16, 64);
        #pragma unroll
        for (int i = 0; i < 3; i++){
            T[nt][i] += __shfl_down(T[nt][i], 32, 64);
            T[nt][i] += __shfl_down(T[nt][i], 16, 64);
        }
    }
    #pragma unroll
    for (int off = 32; off > 0; off >>= 1){
        upx += __shfl_down(upx, off, 64);
        upy += __shfl_down(upy, off, 64);
        upz += __shfl_down(upz, off, 64);
    }
    if (lane < 16){
        sS0[wv][lane]      = s0a[0];
        sS0[wv][16 + lane] = s0a[1];
        #pragma unroll
        for (int i = 0; i < 3; i++){
            sT[wv][lane][i]      = T[0][i];
            sT[wv][16 + lane][i] = T[1][i];
        }
    }
    if (lane == 0){ sUp[wv][0] = upx; sUp[wv][1] = upy; sUp[wv][2] = upz; }
    __syncthreads();
    if (tid == 0){
        float o0 = 0.f;
        for (int j = 0; j < R; j++){
            const float S = sS0[0][j] + sS0[1][j] + sS0[2][j] + sS0[3][j];
            o0 = fmaf(S, W2[j], o0);
        }
        out0h[half*NP + a] = o0 + (float)(NP/2) * B2[0];
        for (int i = 0; i < 3; i++){
            float t = 0.f;
            for (int j = 0; j < R; j++){
                const float Tj = sT[0][j][i] + sT[1][j][i] + sT[2][j][i] + sT[3][j][i];
                t = fmaf(Tj, W2[R + j], t);
            }
            const float Ui = 0.25f * (sUp[0][i] + sUp[1][i] + sUp[2][i] + sUp[3][i]);
            out1h[(half*NP + a)*3 + i] = t + B2[1] * Ui;
        }
    }
}

// ---------------------------------------------------------------------------
// Per-point layer-1 features (sums the split-K halves).
// x0g[b][f] row-major; x1s SoA planes x1s[i][b*C+f].
// ---------------------------------------------------------------------------
__global__ __launch_bounds__(256) void k_point1(
    const float* __restrict__ out0h, const float* __restrict__ out1h,
    const float* __restrict__ si0_w, const float* __restrict__ si0_b,
    const float* __restrict__ si1_w, const float* __restrict__ nl_b,
    float* __restrict__ x0g, float* __restrict__ x1s)
{
    const int b = blockIdx.x*256 + threadIdx.x;
    if (b >= NP) return;
    const float o0 = out0h[b] + out0h[NP + b];
    const float o1x = out1h[b*3+0] + out1h[(NP+b)*3+0];
    const float o1y = out1h[b*3+1] + out1h[(NP+b)*3+1];
    const float o1z = out1h[b*3+2] + out1h[(NP+b)*3+2];
    #pragma unroll
    for (int g = 0; g < C; g++){
        x0g[b*C+g] = eluf(fmaf(o0, si0_w[g], si0_b[g]));
        const float w = si1_w[g];
        const float tx = o1x*w, ty = o1y*w, tz = o1z*w;
        const float n = sqrtf(fmaxf(tx*tx + ty*ty + tz*tz, 1e-8f));
        const float sc = eluf(n + nl_b[g]) / n;
        x1s[0*NP*C + b*C+g] = tx*sc;
        x1s[1*NP*C + b*C+g] = ty*sc;
        x1s[2*NP*C + b*C+g] = tz*sc;
    }
}

// ---------------------------------------------------------------------------
// Layer 2 (MFMA, barrier-free K-loop, SPLIT-K x2): block = (a, half); live
// filters 0 (0x0->0) and 2 (1x1->0) only. Partials c00h/c10h per half;
// k_readout1 sums.
// ---------------------------------------------------------------------------
__global__ __launch_bounds__(256) void k_layer2(
    const float* __restrict__ points,
    const float* __restrict__ W1, const float* __restrict__ B1,
    const float* __restrict__ W2, const float* __restrict__ B2,
    const float* __restrict__ x0g, const float* __restrict__ x1s,
    float* __restrict__ c00h, float* __restrict__ c10h)
{
    __shared__ __align__(16) short sH[4][2][16*40];   // [wave][filter][row*40]
    __shared__ float sRed[4][2][16];

    const int tid  = threadIdx.x;
    const int lane = tid & 63;
    const int wv   = tid >> 6;
    const int l16  = lane & 15;
    const int q    = lane >> 4;
    const int a    = blockIdx.x >> 1;
    const int half = blockIdx.x & 1;
    const float pax = points[a*3+0], pay = points[a*3+1], paz = points[a*3+2];

    bf16x8 w1hi[2][2], w1lo[2][2], w2hi[2], w2lo[2];
    float  b1v[2][2], b2v[2];
    #pragma unroll
    for (int fi = 0; fi < 2; fi++){
        const int fx = (fi == 0) ? 0 : 2;
        #pragma unroll
        for (int nt = 0; nt < 2; nt++){
            load_bfrag<R>(W1 + fx*R*R, q, 2*l16 + nt, w1hi[fi][nt], w1lo[fi][nt]);
            b1v[fi][nt] = B1[fx*R + 2*l16 + nt];
        }
        load_bfrag<C>(W2 + fx*R*C, q, l16, w2hi[fi], w2lo[fi]);
        b2v[fi] = B2[fx*C + l16];
    }

    float acc0 = 0.f, acc1 = 0.f;
    short* sH0 = sH[wv][0];
    short* sH1 = sH[wv][1];

    for (int bt = half*8; bt < half*8 + 8; bt++){
        const int bA = bt*64 + wv*16 + l16;
        const float rx = pax - points[bA*3+0];
        const float ry = pay - points[bA*3+1];
        const float rz = paz - points[bA*3+2];
        const float ss = rx*rx + ry*ry + rz*rz;
        const float dij = sqrtf(ss);
        const float inv = 1.0f / sqrtf(fmaxf(ss, 1e-8f));
        const float ux = rx*inv, uy = ry*inv, uz = rz*inv;  // ==0 on diagonal

        float uxr[4], uyr[4], uzr[4];
        #pragma unroll
        for (int r4 = 0; r4 < 4; r4++){
            const int sl = q*4 + r4;
            uxr[r4] = __shfl(ux, sl, 16);
            uyr[r4] = __shfl(uy, sl, 16);
            uzr[r4] = __shfl(uz, sl, 16);
        }

        // epilogue inputs: rows bE = bt*64+wv*16+q*4+r4, col f = l16
        const int rb = (bt*64 + wv*16 + q*4)*C + l16;
        float x0v[4], udv[4];
        #pragma unroll
        for (int r4 = 0; r4 < 4; r4++){
            x0v[r4] = x0g[rb + r4*C];
            const float v0 = x1s[0*NP*C + rb + r4*C];
            const float v1 = x1s[1*NP*C + rb + r4*C];
            const float v2 = x1s[2*NP*C + rb + r4*C];
            udv[r4] = uxr[r4]*v0 + uyr[r4]*v1 + uzr[r4]*v2;
        }

        const bf16x8 afrag = make_afrag(dij, q);

        // GEMM1 both filters -> packed bf16 H into wave-private LDS
        #pragma unroll
        for (int fi = 0; fi < 2; fi++){
            f32x4 c0 = {b1v[fi][0], b1v[fi][0], b1v[fi][0], b1v[fi][0]};
            c0 = mfma16(afrag, w1hi[fi][0], c0);
            c0 = mfma16(afrag, w1lo[fi][0], c0);
            f32x4 c1 = {b1v[fi][1], b1v[fi][1], b1v[fi][1], b1v[fi][1]};
            c1 = mfma16(afrag, w1hi[fi][1], c1);
            c1 = mfma16(afrag, w1lo[fi][1], c1);
            short* sHf = (fi == 0) ? sH0 : sH1;
            #pragma unroll
            for (int r4 = 0; r4 < 4; r4++){
                const unsigned p = pack2bf(fmaxf(c0[r4], 0.f), fmaxf(c1[r4], 0.f));
                *(unsigned*)&sHf[(q*4+r4)*40 + 2*l16] = p;   // j=2*l16 (lo), 2*l16+1 (hi)
            }
        }
        asm volatile("s_waitcnt lgkmcnt(0)" ::: "memory");   // wave-internal transpose
        #pragma unroll
        for (int fi = 0; fi < 2; fi++){
            const short* sHf = (fi == 0) ? sH0 : sH1;
            const bf16x8 hf = *(const bf16x8*)(sHf + l16*40 + q*8);
            f32x4 d = {b2v[fi], b2v[fi], b2v[fi], b2v[fi]};   // bias pre-seeded
            d = mfma16(hf, w2hi[fi], d);
            d = mfma16(hf, w2lo[fi], d);
            #pragma unroll
            for (int r4 = 0; r4 < 4; r4++){
                if (fi == 0) acc0 = fmaf(d[r4], x0v[r4], acc0);
                else         acc1 = fmaf(d[r4], udv[r4], acc1);
            }
        }
    }

    acc0 += __shfl_down(acc0, 32, 64); acc0 += __shfl_down(acc0, 16, 64);
    acc1 += __shfl_down(acc1, 32, 64); acc1 += __shfl_down(acc1, 16, 64);
    if (lane < 16){ sRed[wv][0][lane] = acc0; sRed[wv][1][lane] = acc1; }
    __syncthreads();
    if (tid < 16)
        c00h[half*NP*C + a*C + tid] =
            sRed[0][0][tid] + sRed[1][0][tid] + sRed[2][0][tid] + sRed[3][0][tid];
    else if (tid < 32){
        const int f = tid - 16;
        c10h[half*NP*C + a*C + f] =
            sRed[0][1][f] + sRed[1][1][f] + sRed[2][1][f] + sRed[3][1][f];
    }
}

// ---------------------------------------------------------------------------
// Readout stage 1: sum split-K halves, per-point layer-2 degree-0 features,
// partial mean pool.
// ---------------------------------------------------------------------------
__global__ __launch_bounds__(256) void k_readout1(
    const float* __restrict__ c00h, const float* __restrict__ c10h,
    const float* __restrict__ si0_w, const float* __restrict__ si0_b,
    float* __restrict__ partial)
{
    __shared__ float sred[4*C];
    const int tid = threadIdx.x;
    const int a = blockIdx.x*256 + tid;
    float v00[C], v10[C];
    #pragma unroll
    for (int f = 0; f < C; f++){
        v00[f] = c00h[a*C+f] + c00h[NP*C + a*C+f];
        v10[f] = c10h[a*C+f] + c10h[NP*C + a*C+f];
    }
    float xg[C];
    #pragma unroll
    for (int g = 0; g < C; g++){
        float s = si0_b[g];
        #pragma unroll
        for (int f = 0; f < C; f++) s = fmaf(v00[f], si0_w[g*2*C + f], s);
        #pragma unroll
        for (int f = 0; f < C; f++) s = fmaf(v10[f], si0_w[g*2*C + C + f], s);
        xg[g] = eluf(s);
    }
    #pragma unroll
    for (int off = 32; off > 0; off >>= 1){
        #pragma unroll
        for (int g = 0; g < C; g++) xg[g] += __shfl_down(xg[g], off, 64);
    }
    const int lane = tid & 63, wv = tid >> 6;
    if (lane == 0){
        #pragma unroll
        for (int g = 0; g < C; g++) sred[wv*C + g] = xg[g];
    }
    __syncthreads();
    if (tid < C)
        partial[blockIdx.x*C + tid] =
            sred[tid] + sred[C + tid] + sred[2*C + tid] + sred[3*C + tid];
}

__global__ void k_readout2(const float* __restrict__ partial,
                           const float* __restrict__ fc_w,
                           const float* __restrict__ fc_b,
                           float* __restrict__ out)
{
    const int o = threadIdx.x;
    if (o < 8){
        float s = fc_b[o];
        #pragma unroll
        for (int g = 0; g < C; g++){
            const float m = (partial[g] + partial[C+g] + partial[2*C+g] + partial[3*C+g])
                            * (1.0f / (float)NP);
            s = fmaf(m, fc_w[g*8 + o], s);
        }
        out[o] = s;
    }
}

extern "C" void kernel_launch(void* const* d_in, const int* in_sizes, int n_in,
                              void* d_out, int out_size, void* d_ws, size_t ws_size,
                              hipStream_t stream)
{
    (void)in_sizes; (void)n_in; (void)out_size; (void)ws_size;
    const float* points   = (const float*)d_in[0];
    const float* l1_W1    = (const float*)d_in[1];
    const float* l1_B1    = (const float*)d_in[2];
    const float* l1_W2    = (const float*)d_in[3];
    const float* l1_B2    = (const float*)d_in[4];
    const float* l1_si0_w = (const float*)d_in[5];
    const float* l1_si0_b = (const float*)d_in[6];
    const float* l1_si1_w = (const float*)d_in[7];
    const float* l1_nl_b  = (const float*)d_in[8];
    const float* l2_W1    = (const float*)d_in[9];
    const float* l2_B1    = (const float*)d_in[10];
    const float* l2_W2    = (const float*)d_in[11];
    const float* l2_B2    = (const float*)d_in[12];
    const float* l2_si0_w = (const float*)d_in[13];
    const float* l2_si0_b = (const float*)d_in[14];
    // d_in[15] l2_si1_w, d_in[16] l2_nl_b: dead code in the reference readout
    const float* fc_w     = (const float*)d_in[17];
    const float* fc_b     = (const float*)d_in[18];

    float* ws      = (float*)d_ws;
    float* out0h   = ws;                    // 2*NP
    float* out1h   = out0h + 2*NP;          // 2*NP*3
    float* x0g     = out1h + 2*NP*3;        // NP*C
    float* x1s     = x0g + NP*C;            // 3*NP*C (SoA planes)
    float* c00h    = x1s + 3*NP*C;          // 2*NP*C
    float* c10h    = c00h + 2*NP*C;         // 2*NP*C
    float* partial = c10h + 2*NP*C;         // 4*C

    k_layer1<<<2*NP, 256, 0, stream>>>(points, l1_W1, l1_B1, l1_W2, l1_B2, out0h, out1h);
    k_point1<<<NP/256, 256, 0, stream>>>(out0h, out1h, l1_si0_w, l1_si0_b, l1_si1_w, l1_nl_b, x0g, x1s);
    k_layer2<<<2*NP, 256, 0, stream>>>(points, l2_W1, l2_B1, l2_W2, l2_B2, x0g, x1s, c00h, c10h);
    k_readout1<<<NP/256, 256, 0, stream>>>(c00h, c10h, l2_si0_w, l2_si0_b, partial);
    k_readout2<<<1, 64, 0, stream>>>(partial, fc_w, fc_b, (float*)d_out);
}